// Round 15
// baseline (127.514 us; speedup 1.0000x reference)
//
#include <hip/hip_runtime.h>
#include <hip/hip_bf16.h>
#include <cmath>

#define NN 8192
#define FIN 256
#define FOUT 128
#define NCH 8
#define JC (NN / NCH)        // 1024 j per chunk
#define WPC (JC / 64)        // 16 windows (of 64 j) per chunk
#define MP 17                // mask LDS row pitch (u64)
#define LOG2E 1.44269504f

typedef short short8 __attribute__((ext_vector_type(8)));
typedef float f32x4 __attribute__((ext_vector_type(4)));
typedef float f32x16 __attribute__((ext_vector_type(16)));
typedef unsigned long long u64;

static __device__ __forceinline__ unsigned short f2bf(float f) {
    unsigned u = __float_as_uint(f);
    u += 0x7fffu + ((u >> 16) & 1u);
    return (unsigned short)(u >> 16);
}

static __device__ __forceinline__ unsigned cvtpk(float lo, float hi) {
    unsigned r;
    asm("v_cvt_pk_bf16_f32 %0, %1, %2" : "=v"(r) : "v"(lo), "v"(hi));
    return r;
}

// ---------------------------------------------------------------------------
// Stage kernel (heterogeneous): blocks 0..127 = pass_a; blocks 128+ = compress
// (adj -> bm3, row-dense streaming, 256B contiguous per thread).
// bm3 layout [chunk][row][16 u64], plain bit order.
// ---------------------------------------------------------------------------
__global__ __launch_bounds__(256, 2)
void gat_stage(const float* __restrict__ input, const int* __restrict__ adj,
               const float* __restrict__ W, const float* __restrict__ Wb,
               const float* __restrict__ aw, const float* __restrict__ ab,
               unsigned short* __restrict__ hT4, float* __restrict__ s_out,
               float* __restrict__ t_out, u64* __restrict__ bm3) {
    __shared__ float sred[4][32];
    __shared__ float tred[4][32];
    const int tid = threadIdx.x;

    if (blockIdx.x >= 128) {
        const int row = (blockIdx.x - 128) * 2 + (tid >> 7);
        const int wing = tid & 127;
        const int4* p = (const int4*)(adj + (size_t)row * NN + wing * 64);
        u64 m = 0;
        #pragma unroll
        for (int q = 0; q < 16; ++q) {
            const int4 v = p[q];
            m |= (u64)(v.x > 0) << (q * 4 + 0);
            m |= (u64)(v.y > 0) << (q * 4 + 1);
            m |= (u64)(v.z > 0) << (q * 4 + 2);
            m |= (u64)(v.w > 0) << (q * 4 + 3);
        }
        const int ch = wing >> 4, winc = wing & 15;
        bm3[((size_t)ch * NN + row) * 16 + winc] = m;
        return;
    }

    const int w = tid >> 6, l = tid & 63;
    const int l5 = l >> 5, l31 = l & 31;
    const int nt = w >> 1, mh = w & 1;
    const int bx = blockIdx.x;
    const int i = bx * 64 + nt * 32 + l31;

    f32x16 acc0 = {}; f32x16 acc1 = {};
    #pragma unroll
    for (int ks = 0; ks < FIN / 16; ++ks) {
        const int c0 = ks * 16 + l5 * 8;
        const float4 b0 = *(const float4*)(input + (size_t)i * FIN + c0);
        const float4 b1 = *(const float4*)(input + (size_t)i * FIN + c0 + 4);
        short8 bf;
        bf[0]=(short)f2bf(b0.x); bf[1]=(short)f2bf(b0.y); bf[2]=(short)f2bf(b0.z); bf[3]=(short)f2bf(b0.w);
        bf[4]=(short)f2bf(b1.x); bf[5]=(short)f2bf(b1.y); bf[6]=(short)f2bf(b1.z); bf[7]=(short)f2bf(b1.w);
        {
            const int kcol = l31 + 32 * (2 * mh + 0);
            const float4 a0 = *(const float4*)(W + (size_t)kcol * FIN + c0);
            const float4 a1 = *(const float4*)(W + (size_t)kcol * FIN + c0 + 4);
            short8 af;
            af[0]=(short)f2bf(a0.x); af[1]=(short)f2bf(a0.y); af[2]=(short)f2bf(a0.z); af[3]=(short)f2bf(a0.w);
            af[4]=(short)f2bf(a1.x); af[5]=(short)f2bf(a1.y); af[6]=(short)f2bf(a1.z); af[7]=(short)f2bf(a1.w);
            acc0 = __builtin_amdgcn_mfma_f32_32x32x16_bf16(af, bf, acc0, 0, 0, 0);
        }
        {
            const int kcol = l31 + 32 * (2 * mh + 1);
            const float4 a0 = *(const float4*)(W + (size_t)kcol * FIN + c0);
            const float4 a1 = *(const float4*)(W + (size_t)kcol * FIN + c0 + 4);
            short8 af;
            af[0]=(short)f2bf(a0.x); af[1]=(short)f2bf(a0.y); af[2]=(short)f2bf(a0.z); af[3]=(short)f2bf(a0.w);
            af[4]=(short)f2bf(a1.x); af[5]=(short)f2bf(a1.y); af[6]=(short)f2bf(a1.z); af[7]=(short)f2bf(a1.w);
            acc1 = __builtin_amdgcn_mfma_f32_32x32x16_bf16(af, bf, acc1, 0, 0, 0);
        }
    }
    float sacc = 0.f, tacc = 0.f;
    const int jt = bx * 2 + nt;
    const int lane_half = 16 * (l31 >> 3);
    const int e4 = l31 & 7;
    #pragma unroll
    for (int m = 0; m < 2; ++m) {
        #pragma unroll
        for (int r = 0; r < 16; ++r) {
            const int kcol = 32 * (2 * mh + m) + 4 * l5 + (r & 3) + 8 * (r >> 2);
            const float hv = (m ? acc1[r] : acc0[r]) + Wb[kcol];
            const int lane4 = (kcol & 15) + lane_half;
            hT4[(size_t)(jt * 8 + (kcol >> 4)) * 512 + lane4 * 8 + e4] = f2bf(hv);
            sacc += hv * aw[kcol];
            tacc += hv * aw[FOUT + kcol];
        }
    }
    sacc += __shfl_xor(sacc, 32);
    tacc += __shfl_xor(tacc, 32);
    if (l < 32) { sred[w][l] = sacc; tred[w][l] = tacc; }
    __syncthreads();
    if (mh == 0 && l < 32) {
        s_out[i] = (sred[w][l] + sred[w + 1][l]) * LOG2E;
        t_out[i] = (tred[w][l] + tred[w + 1][l] + ab[0]) * LOG2E;
    }
}

// ---------------------------------------------------------------------------
// Pass B v4: wave owns 32 ROWS (2 i-tiles) x 128 f -> af LDS reads amortized
// over 2x rows (halves total LDS traffic). Block = 4 waves x 128 rows x chunk;
// grid 512 = 2 blocks/CU, one generation. h window tiles double-buffered in
// LDS (global prefetch each window); masks staged ONCE in LDS; t in LDS.
// Denominators via MFMA with all-ones A-frag. Direct coalesced stores.
// ---------------------------------------------------------------------------
#define PBUILD(SI, MK, BF)                                                      \
    {                                                                           \
        float x, p0, p1, p2, p3, p4, p5, p6, p7;                                \
        x = (SI) + t0.x; x = fmaxf(x, 0.2f * x); p0 = exp2f(x);                 \
        p0 = ((MK) & 1u)   ? p0 : 0.f;                                          \
        x = (SI) + t0.y; x = fmaxf(x, 0.2f * x); p1 = exp2f(x);                 \
        p1 = ((MK) & 2u)   ? p1 : 0.f;                                          \
        x = (SI) + t0.z; x = fmaxf(x, 0.2f * x); p2 = exp2f(x);                 \
        p2 = ((MK) & 4u)   ? p2 : 0.f;                                          \
        x = (SI) + t0.w; x = fmaxf(x, 0.2f * x); p3 = exp2f(x);                 \
        p3 = ((MK) & 8u)   ? p3 : 0.f;                                          \
        x = (SI) + t1.x; x = fmaxf(x, 0.2f * x); p4 = exp2f(x);                 \
        p4 = ((MK) & 16u)  ? p4 : 0.f;                                          \
        x = (SI) + t1.y; x = fmaxf(x, 0.2f * x); p5 = exp2f(x);                 \
        p5 = ((MK) & 32u)  ? p5 : 0.f;                                          \
        x = (SI) + t1.z; x = fmaxf(x, 0.2f * x); p6 = exp2f(x);                 \
        p6 = ((MK) & 64u)  ? p6 : 0.f;                                          \
        x = (SI) + t1.w; x = fmaxf(x, 0.2f * x); p7 = exp2f(x);                 \
        p7 = ((MK) & 128u) ? p7 : 0.f;                                          \
        union { int4 i4; short8 s8; } bu;                                       \
        bu.i4.x = (int)cvtpk(p0, p1);                                           \
        bu.i4.y = (int)cvtpk(p2, p3);                                           \
        bu.i4.z = (int)cvtpk(p4, p5);                                           \
        bu.i4.w = (int)cvtpk(p6, p7);                                           \
        BF = bu.s8;                                                             \
    }

__global__ __launch_bounds__(256, 2)
void gat_pass_b(const u64* __restrict__ bm3, const unsigned short* __restrict__ hT4,
                const float* __restrict__ s_in, const float* __restrict__ t_in,
                float* __restrict__ numw, float* __restrict__ dpart) {
    __shared__ int4 hbuf[2][1024];           // 32 KB
    __shared__ float tlds[JC];               // 4 KB
    __shared__ u64 mlds[128 * MP];           // 17 KB
    const int tid = threadIdx.x;
    const int wv = tid >> 6, l = tid & 63;
    const int li = l & 15;
    const int kq = l >> 4;
    const int i0 = blockIdx.x * 128;
    const int chunk = blockIdx.y;
    const int iw = i0 + wv * 32;

    // stage t
    *(float4*)&tlds[tid * 4] = *(const float4*)(t_in + chunk * JC + tid * 4);
    // stage masks: 16KB contiguous -> mlds[128][17]
    {
        const uint4* src = (const uint4*)(bm3 + ((size_t)chunk * NN + i0) * 16) + tid * 4;
        const uint4 q0 = src[0], q1 = src[1], q2 = src[2], q3 = src[3];
        u64* dst = mlds + (tid >> 1) * MP + (tid & 1) * 8;
        *(uint4*)(dst)     = q0;
        *(uint4*)(dst + 2) = q1;
        *(uint4*)(dst + 4) = q2;
        *(uint4*)(dst + 6) = q3;
    }
    // stage window 0 h-slice
    const int4* gsrc = (const int4*)hT4 + (size_t)chunk * 32 * 512;
    hbuf[0][tid]       = gsrc[tid];
    hbuf[0][tid + 256] = gsrc[tid + 256];
    hbuf[0][tid + 512] = gsrc[tid + 512];
    hbuf[0][tid + 768] = gsrc[tid + 768];

    const float si0 = s_in[iw + li];
    const float si1 = s_in[iw + 16 + li];
    const int mrow0 = (wv * 32 + li) * MP;
    const int mrow1 = (wv * 32 + 16 + li) * MP;
    __syncthreads();

    f32x4 a00 = {}, a01 = {}, a02 = {}, a03 = {}, a04 = {}, a05 = {}, a06 = {}, a07 = {};
    f32x4 a10 = {}, a11 = {}, a12 = {}, a13 = {}, a14 = {}, a15 = {}, a16 = {}, a17 = {};
    f32x4 d0 = {}, d1 = {};
    short8 ones;
    #pragma unroll
    for (int e = 0; e < 8; ++e) ones[e] = (short)0x3F80;

    for (int w = 0; w < WPC; ++w) {
        const int buf = w & 1;
        int4 g0, g1, g2, g3;
        if (w + 1 < WPC) {
            const int4* gn = gsrc + (size_t)(w + 1) * 1024;
            g0 = gn[tid];
            g1 = gn[tid + 256];
            g2 = gn[tid + 512];
            g3 = gn[tid + 768];
        }
        const u64 m0 = mlds[mrow0 + w];
        const u64 m1 = mlds[mrow1 + w];
        #pragma unroll
        for (int kk = 0; kk < 2; ++kk) {
            const int4* hb = &hbuf[buf][kk * 512];
            const short8 af0 = *(const short8*)&hb[0 * 64 + l];
            const short8 af1 = *(const short8*)&hb[1 * 64 + l];
            const short8 af2 = *(const short8*)&hb[2 * 64 + l];
            const short8 af3 = *(const short8*)&hb[3 * 64 + l];
            const short8 af4 = *(const short8*)&hb[4 * 64 + l];
            const short8 af5 = *(const short8*)&hb[5 * 64 + l];
            const short8 af6 = *(const short8*)&hb[6 * 64 + l];
            const short8 af7 = *(const short8*)&hb[7 * 64 + l];
            const int tix = w * 64 + kk * 32 + kq * 8;
            const float4 t0 = *(const float4*)&tlds[tix];
            const float4 t1 = *(const float4*)&tlds[tix + 4];
            const unsigned mk0 = (unsigned)(m0 >> (kk * 32 + kq * 8)) & 0xffu;
            const unsigned mk1 = (unsigned)(m1 >> (kk * 32 + kq * 8)) & 0xffu;

            short8 bf0, bf1;
            PBUILD(si0, mk0, bf0)
            PBUILD(si1, mk1, bf1)

            a00 = __builtin_amdgcn_mfma_f32_16x16x32_bf16(af0, bf0, a00, 0, 0, 0);
            a01 = __builtin_amdgcn_mfma_f32_16x16x32_bf16(af1, bf0, a01, 0, 0, 0);
            a02 = __builtin_amdgcn_mfma_f32_16x16x32_bf16(af2, bf0, a02, 0, 0, 0);
            a03 = __builtin_amdgcn_mfma_f32_16x16x32_bf16(af3, bf0, a03, 0, 0, 0);
            a04 = __builtin_amdgcn_mfma_f32_16x16x32_bf16(af4, bf0, a04, 0, 0, 0);
            a05 = __builtin_amdgcn_mfma_f32_16x16x32_bf16(af5, bf0, a05, 0, 0, 0);
            a06 = __builtin_amdgcn_mfma_f32_16x16x32_bf16(af6, bf0, a06, 0, 0, 0);
            a07 = __builtin_amdgcn_mfma_f32_16x16x32_bf16(af7, bf0, a07, 0, 0, 0);
            d0  = __builtin_amdgcn_mfma_f32_16x16x32_bf16(ones, bf0, d0, 0, 0, 0);
            a10 = __builtin_amdgcn_mfma_f32_16x16x32_bf16(af0, bf1, a10, 0, 0, 0);
            a11 = __builtin_amdgcn_mfma_f32_16x16x32_bf16(af1, bf1, a11, 0, 0, 0);
            a12 = __builtin_amdgcn_mfma_f32_16x16x32_bf16(af2, bf1, a12, 0, 0, 0);
            a13 = __builtin_amdgcn_mfma_f32_16x16x32_bf16(af3, bf1, a13, 0, 0, 0);
            a14 = __builtin_amdgcn_mfma_f32_16x16x32_bf16(af4, bf1, a14, 0, 0, 0);
            a15 = __builtin_amdgcn_mfma_f32_16x16x32_bf16(af5, bf1, a15, 0, 0, 0);
            a16 = __builtin_amdgcn_mfma_f32_16x16x32_bf16(af6, bf1, a16, 0, 0, 0);
            a17 = __builtin_amdgcn_mfma_f32_16x16x32_bf16(af7, bf1, a17, 0, 0, 0);
            d1  = __builtin_amdgcn_mfma_f32_16x16x32_bf16(ones, bf1, d1, 0, 0, 0);
        }
        if (w + 1 < WPC) {
            hbuf[buf ^ 1][tid]       = g0;
            hbuf[buf ^ 1][tid + 256] = g1;
            hbuf[buf ^ 1][tid + 512] = g2;
            hbuf[buf ^ 1][tid + 768] = g3;
        }
        __syncthreads();
    }

    // epilogue: direct coalesced stores
    float* nb = numw + (size_t)chunk * FOUT * NN;
    const int ir0 = iw + li;
    const int ir1 = iw + 16 + li;
    #pragma unroll
    for (int r = 0; r < 4; ++r) {
        const int fr = kq * 4 + r;
        nb[(size_t)(fr      ) * NN + ir0] = a00[r];
        nb[(size_t)(fr + 16 ) * NN + ir0] = a01[r];
        nb[(size_t)(fr + 32 ) * NN + ir0] = a02[r];
        nb[(size_t)(fr + 48 ) * NN + ir0] = a03[r];
        nb[(size_t)(fr + 64 ) * NN + ir0] = a04[r];
        nb[(size_t)(fr + 80 ) * NN + ir0] = a05[r];
        nb[(size_t)(fr + 96 ) * NN + ir0] = a06[r];
        nb[(size_t)(fr + 112) * NN + ir0] = a07[r];
        nb[(size_t)(fr      ) * NN + ir1] = a10[r];
        nb[(size_t)(fr + 16 ) * NN + ir1] = a11[r];
        nb[(size_t)(fr + 32 ) * NN + ir1] = a12[r];
        nb[(size_t)(fr + 48 ) * NN + ir1] = a13[r];
        nb[(size_t)(fr + 64 ) * NN + ir1] = a14[r];
        nb[(size_t)(fr + 80 ) * NN + ir1] = a15[r];
        nb[(size_t)(fr + 96 ) * NN + ir1] = a16[r];
        nb[(size_t)(fr + 112) * NN + ir1] = a17[r];
    }
    if (kq == 0) {
        dpart[(size_t)chunk * NN + ir0] = d0[0];
        dpart[(size_t)chunk * NN + ir1] = d1[0];
    }
}

// ---------------------------------------------------------------------------
// Pass C: out[i][f] = elu( sum_c numw[c][f][i] / sum_c dpart[c][i] )
// ---------------------------------------------------------------------------
__global__ __launch_bounds__(256)
void gat_reduce(const float* __restrict__ numw, const float* __restrict__ dpart,
                float* __restrict__ out, int nchunk) {
    __shared__ float tile[FOUT * 33];
    __shared__ float dent[32];
    const int t = threadIdx.x;
    const int i0 = blockIdx.x * 32;
    if (t < 32) {
        float d = 0.f;
        for (int c = 0; c < nchunk; ++c) d += dpart[(size_t)c * NN + i0 + t];
        dent[t] = d;
    }
    __syncthreads();
    #pragma unroll
    for (int e = 0; e < 4; ++e) {
        const int f = e * 32 + (t >> 3);
        const int io = (t & 7) * 4;
        float4 s = {0.f, 0.f, 0.f, 0.f};
        for (int c = 0; c < nchunk; ++c) {
            const float4 v = *(const float4*)(numw + ((size_t)c * FOUT + f) * NN + i0 + io);
            s.x += v.x; s.y += v.y; s.z += v.z; s.w += v.w;
        }
        float v;
        v = s.x / dent[io + 0]; tile[f * 33 + io + 0] = (v > 0.f) ? v : expm1f(v);
        v = s.y / dent[io + 1]; tile[f * 33 + io + 1] = (v > 0.f) ? v : expm1f(v);
        v = s.z / dent[io + 2]; tile[f * 33 + io + 2] = (v > 0.f) ? v : expm1f(v);
        v = s.w / dent[io + 3]; tile[f * 33 + io + 3] = (v > 0.f) ? v : expm1f(v);
    }
    __syncthreads();
    #pragma unroll
    for (int e = 0; e < 4; ++e) {
        const int row = (t >> 5) * 4 + e;
        const int fo = (t & 31) * 4;
        const float4 v = { tile[(fo + 0) * 33 + row], tile[(fo + 1) * 33 + row],
                           tile[(fo + 2) * 33 + row], tile[(fo + 3) * 33 + row] };
        *(float4*)(out + (size_t)(i0 + row) * FOUT + fo) = v;
    }
}

// ---------------------------------------------------------------------------
extern "C" void kernel_launch(void* const* d_in, const int* in_sizes, int n_in,
                              void* d_out, int out_size, void* d_ws, size_t ws_size,
                              hipStream_t stream) {
    const float* input = (const float*)d_in[0];
    const int*   adj   = (const int*)d_in[1];
    const float* Ww    = (const float*)d_in[2];
    const float* Wb    = (const float*)d_in[3];
    const float* aw    = (const float*)d_in[4];
    const float* ab    = (const float*)d_in[5];
    float* out = (float*)d_out;

    char* ws = (char*)d_ws;
    unsigned short* hT4 = (unsigned short*)ws;               // 2 MB
    float* s_buf = (float*)(ws + (size_t)FOUT * NN * 2);     // 32 KB
    float* t_buf = s_buf + NN;                               // 32 KB
    float* dpart = t_buf + NN;                               // NCH*32 KB
    float* numw = dpart + (size_t)NCH * NN;                  // NCH*4 MB
    u64* bm3 = (u64*)(numw + (size_t)NCH * NN * FOUT);       // 8 MB

    gat_stage<<<dim3(128 + NN / 2), 256, 0, stream>>>(input, adj, Ww, Wb, aw, ab,
                                                      hT4, s_buf, t_buf, bm3);
    gat_pass_b<<<dim3(NN / 128, NCH), 256, 0, stream>>>(bm3, hT4, s_buf, t_buf, numw, dpart);
    gat_reduce<<<dim3(NN / 32), 256, 0, stream>>>(numw, dpart, out, NCH);
}